// Round 12
// baseline (28410.611 us; speedup 1.0000x reference)
//
#include <hip/hip_runtime.h>
#include <hip/hip_bf16.h>
#include <math.h>

// MogLSTM S=512, B=64, E=H=1024. R12: 6 nodes/step, all 1024-thread blocks
// (4 waves/SIMD for cold-L2 latency hiding), gate GEMM split across nodes:
// node5 = {mog P5 || z_h = h4@W_h -> zbuf}, node6 = {z_x = x5@W_x + zbuf +
// bias -> LSTM}. W read exactly once per step (16 MB per heavy node).
// Numerics = r8-r11 recipe (absmax 0.0039): bf16 hi+lo 4-term products,
// fp32 masters, accurate expf/tanhf. Fragment mappings verbatim from the
// r10/r11-verified kernels; only fp32 partial-sum grouping changes.

using bf16   = __bf16;
using bf16x8 = __attribute__((ext_vector_type(8))) __bf16;
using f32x4  = __attribute__((ext_vector_type(4))) float;

#define MFMA16(a,b,c) __builtin_amdgcn_mfma_f32_16x16x32_bf16((a),(b),(c),0,0,0)

__device__ __forceinline__ float fsig(float x) { return 1.f / (1.f + expf(-x)); }

// ---------------- prologue: Q/R hi+lo split, zero state ----------------
__global__ void prep(const float* __restrict__ Q, const float* __restrict__ R,
                     bf16* __restrict__ Qh, bf16* __restrict__ Ql,
                     bf16* __restrict__ Rh, bf16* __restrict__ Rl,
                     float* __restrict__ hM, float* __restrict__ cM,
                     bf16* __restrict__ Nh, bf16* __restrict__ Nl) {
  const long tid = (long)blockIdx.x * blockDim.x + threadIdx.x;
  const long nth = (long)gridDim.x * blockDim.x;
  for (long i = tid; i < 1024L * 1024 / 4; i += nth) {
    float4 v = ((const float4*)Q)[i];
    bf16 a0 = (bf16)v.x, a1 = (bf16)v.y, a2 = (bf16)v.z, a3 = (bf16)v.w;
    Qh[i*4+0] = a0; Qh[i*4+1] = a1; Qh[i*4+2] = a2; Qh[i*4+3] = a3;
    Ql[i*4+0] = (bf16)(v.x - (float)a0); Ql[i*4+1] = (bf16)(v.y - (float)a1);
    Ql[i*4+2] = (bf16)(v.z - (float)a2); Ql[i*4+3] = (bf16)(v.w - (float)a3);
    float4 u = ((const float4*)R)[i];
    bf16 b0 = (bf16)u.x, b1 = (bf16)u.y, b2 = (bf16)u.z, b3 = (bf16)u.w;
    Rh[i*4+0] = b0; Rh[i*4+1] = b1; Rh[i*4+2] = b2; Rh[i*4+3] = b3;
    Rl[i*4+0] = (bf16)(u.x - (float)b0); Rl[i*4+1] = (bf16)(u.y - (float)b1);
    Rl[i*4+2] = (bf16)(u.z - (float)b2); Rl[i*4+3] = (bf16)(u.w - (float)b3);
  }
  for (long i = tid; i < 64L * 1024; i += nth) {
    hM[i] = 0.f; cM[i] = 0.f; Nh[i] = (bf16)0.f; Nl[i] = (bf16)0.f;
  }
}

// ---------------- mog GEMM body (shared by mog_phase and node5) -----------
// 1024 thr: wave w (0..15) = K-slice of 64 (2 ksteps). Epilogue mapping
// verbatim from r9-r11: col = 16c + (l&15), row = 16mt + (l>>4)*4 + q.
__device__ __forceinline__ void mog_body(
    int mt, int c, int tid, char* smem,
    const bf16* __restrict__ Ah, const bf16* __restrict__ Al,
    const bf16* __restrict__ Bh, const bf16* __restrict__ Bl,
    const float* __restrict__ mult, float* __restrict__ dstM,
    bf16* __restrict__ Dh, bf16* __restrict__ Dl) {
  f32x4* red = (f32x4*)smem;   // [15][64]
  const int l = tid & 63, w = tid >> 6;
  const int r16 = l & 15, kg = l >> 4;
  const size_t kb = (size_t)w * 64 + kg * 8;
  const bf16* bhp = Bh + (size_t)(16 * c + r16) * 1024 + kb;
  const bf16* blp = Bl + (size_t)(16 * c + r16) * 1024 + kb;
  const bf16* ahp = Ah + (size_t)(16 * mt + r16) * 1024 + kb;
  const bf16* alp = Al + (size_t)(16 * mt + r16) * 1024 + kb;
  f32x4 acc = {};
#pragma unroll
  for (int ks = 0; ks < 2; ++ks) {
    bf16x8 bh = *(const bf16x8*)(bhp + ks * 32);
    bf16x8 bl = *(const bf16x8*)(blp + ks * 32);
    bf16x8 ah = *(const bf16x8*)(ahp + ks * 32);
    bf16x8 al = *(const bf16x8*)(alp + ks * 32);
    acc = MFMA16(al, bl, acc);
    acc = MFMA16(al, bh, acc);
    acc = MFMA16(ah, bl, acc);
    acc = MFMA16(ah, bh, acc);
  }
  if (w) red[(w - 1) * 64 + l] = acc;
  __syncthreads();
  if (w == 0) {
#pragma unroll
    for (int kk = 0; kk < 15; ++kk) acc += red[kk * 64 + l];
    const int col = 16 * c + r16;
#pragma unroll
    for (int q = 0; q < 4; ++q) {
      const int row = 16 * mt + kg * 4 + q;
      const size_t idx = (size_t)row * 1024 + col;
      float v = 2.f * fsig(acc[q]) * mult[idx];
      dstM[idx] = v;
      bf16 hi = (bf16)v;
      Dh[idx] = hi;
      Dl[idx] = (bf16)(v - (float)hi);
    }
  }
}

__global__ __launch_bounds__(1024) void mog_phase(
    const bf16* __restrict__ Ah, const bf16* __restrict__ Al,
    const bf16* __restrict__ Bh, const bf16* __restrict__ Bl,
    const float* __restrict__ mult, float* __restrict__ dstM,
    bf16* __restrict__ Dh, bf16* __restrict__ Dl) {
  __shared__ __align__(16) char smem[15 * 64 * 16];
  mog_body(blockIdx.x >> 6, blockIdx.x & 63, threadIdx.x, smem,
           Ah, Al, Bh, Bl, mult, dstM, Dh, Dl);
}

// ---------------- half-gate GEMM body ----------------
// WG g owns hcols 4g..4g+3 for all 4 gates (B-col r16 -> W row
// (r16>>2)*1024 + 4g + (r16&3), verbatim r10/r11). K = one 1024 half
// (khalf: 0 = x half, 1 = h half), 16 waves -> K=64 each (2 ksteps).
// Partials left in LDS red[16][4][64]; caller does the epilogue.
__device__ __forceinline__ void halfgate_body(
    int g, int tid, f32x4* red,
    const bf16* __restrict__ Abh, const bf16* __restrict__ Abl,
    const float* __restrict__ Wf, int khalf) {
  const int l = tid & 63, w = tid >> 6;
  const int r16 = l & 15, kg = l >> 4;
  const size_t kb = (size_t)w * 64 + kg * 8;
  const size_t wrow = (size_t)(r16 >> 2) * 1024 + 4 * g + (r16 & 3);
  const float* wp = Wf + wrow * 2048 + (size_t)khalf * 1024 + kb;
  f32x4 acc[4] = {};
#pragma unroll
  for (int ks = 0; ks < 2; ++ks) {
    f32x4 w0 = *(const f32x4*)(wp + ks * 32);
    f32x4 w1 = *(const f32x4*)(wp + ks * 32 + 4);
    bf16x8 bh, bl;
#pragma unroll
    for (int e = 0; e < 4; ++e) {
      bf16 t0 = (bf16)w0[e]; bh[e] = t0;     bl[e] = (bf16)(w0[e] - (float)t0);
      bf16 t1 = (bf16)w1[e]; bh[4 + e] = t1; bl[4 + e] = (bf16)(w1[e] - (float)t1);
    }
#pragma unroll
    for (int m = 0; m < 4; ++m) {
      bf16x8 ah = *(const bf16x8*)(Abh + (size_t)(16 * m + r16) * 1024 + kb + ks * 32);
      bf16x8 al = *(const bf16x8*)(Abl + (size_t)(16 * m + r16) * 1024 + kb + ks * 32);
      acc[m] = MFMA16(al, bl, acc[m]);
      acc[m] = MFMA16(al, bh, acc[m]);
      acc[m] = MFMA16(ah, bl, acc[m]);
      acc[m] = MFMA16(ah, bh, acc[m]);
    }
  }
#pragma unroll
  for (int m = 0; m < 4; ++m) red[(w * 4 + m) * 64 + l] = acc[m];
  __syncthreads();
}

// ---------------- node 5: mog P5 (bids 0..255) || z_h (bids 256..511) -----
__global__ __launch_bounds__(1024) void mog5_zh(
    const bf16* __restrict__ Hh, const bf16* __restrict__ Hl,   // h4 bands
    const bf16* __restrict__ Qh, const bf16* __restrict__ Ql,
    const float* __restrict__ xM, float* __restrict__ dstM,
    bf16* __restrict__ Xh, bf16* __restrict__ Xl,
    const float* __restrict__ Wf, float* __restrict__ zbuf) {
  __shared__ __align__(16) char smem[16 * 4 * 64 * 16];   // 64 KB (union)
  const int bid = blockIdx.x, tid = threadIdx.x;
  if (bid < 256) {
    mog_body(bid >> 6, bid & 63, tid, smem, Hh, Hl, Qh, Ql, xM, dstM, Xh, Xl);
    return;
  }
  const int g = bid - 256;
  f32x4* red = (f32x4*)smem;
  halfgate_body(g, tid, red, Hh, Hl, Wf, /*khalf=*/1);
  if (tid < 256) {
    const int row = tid >> 2, hc = tid & 3;
    const int m = row >> 4, rem = row & 15;
    const int kgq = rem >> 2, q = rem & 3;
#pragma unroll
    for (int gg = 0; gg < 4; ++gg) {
      const int lane = kgq * 16 + gg * 4 + hc;
      float s = red[(0 * 4 + m) * 64 + lane][q];
#pragma unroll
      for (int kk = 1; kk < 16; ++kk) s += red[(kk * 4 + m) * 64 + lane][q];
      zbuf[(size_t)row * 4096 + gg * 1024 + 4 * g + hc] = s;
    }
  }
}

// ---------------- node 6: z_x + zbuf + bias -> LSTM update ----------------
__global__ __launch_bounds__(1024) void gate_x(
    const bf16* __restrict__ Xh, const bf16* __restrict__ Xl,   // x5 bands
    const float* __restrict__ Wf, const float* __restrict__ zbuf,
    const float* __restrict__ ball, float* __restrict__ cM,
    float* __restrict__ hM, bf16* __restrict__ Nh, bf16* __restrict__ Nl,
    float* __restrict__ out, int t) {
  __shared__ __align__(16) char smem[16 * 4 * 64 * 16];   // 64 KB
  const int g = blockIdx.x, tid = threadIdx.x;
  f32x4* red = (f32x4*)smem;
  halfgate_body(g, tid, red, Xh, Xl, Wf, /*khalf=*/0);
  if (tid < 256) {
    const int row = tid >> 2, hc = tid & 3;
    const int m = row >> 4, rem = row & 15;
    const int kgq = rem >> 2, q = rem & 3;
    const int hcg = 4 * g + hc;
    float z[4];
#pragma unroll
    for (int gg = 0; gg < 4; ++gg) {
      const int lane = kgq * 16 + gg * 4 + hc;
      float s = red[(0 * 4 + m) * 64 + lane][q];
#pragma unroll
      for (int kk = 1; kk < 16; ++kk) s += red[(kk * 4 + m) * 64 + lane][q];
      z[gg] = s + zbuf[(size_t)row * 4096 + gg * 1024 + hcg] + ball[gg * 1024 + hcg];
    }
    const size_t idx = (size_t)row * 1024 + hcg;
    const float cc = fsig(z[1]) * cM[idx] + fsig(z[0]) * tanhf(z[2]);
    const float hh = fsig(z[3]) * tanhf(cc);
    cM[idx] = cc;
    hM[idx] = hh;
    bf16 hib = (bf16)hh;
    Nh[idx] = hib;
    Nl[idx] = (bf16)(hh - (float)hib);
    out[(size_t)t * 65536 + idx] = hh;
    if (t == 511) {
      out[(size_t)512 * 65536 + idx] = hh;
      out[(size_t)512 * 65536 + 65536 + idx] = cc;
    }
  }
}

extern "C" void kernel_launch(void* const* d_in, const int* in_sizes, int n_in,
                              void* d_out, int out_size, void* d_ws, size_t ws_size,
                              hipStream_t stream) {
  (void)in_sizes; (void)n_in; (void)out_size; (void)ws_size;
  const float* x    = (const float*)d_in[0];
  const float* Wall = (const float*)d_in[1];
  const float* ball = (const float*)d_in[2];
  const float* Q    = (const float*)d_in[3];
  const float* R    = (const float*)d_in[4];
  float* out = (float*)d_out;

  char* ws = (char*)d_ws;
  size_t off = 0;
  bf16* Qh = (bf16*)(ws + off); off += (size_t)1024 * 1024 * 2;   // 2 MB
  bf16* Ql = (bf16*)(ws + off); off += (size_t)1024 * 1024 * 2;
  bf16* Rh = (bf16*)(ws + off); off += (size_t)1024 * 1024 * 2;
  bf16* Rl = (bf16*)(ws + off); off += (size_t)1024 * 1024 * 2;
  bf16* Xh = (bf16*)(ws + off); off += (size_t)64 * 1024 * 2;     // 128 KB each
  bf16* Xl = (bf16*)(ws + off); off += (size_t)64 * 1024 * 2;
  bf16* Hh = (bf16*)(ws + off); off += (size_t)64 * 1024 * 2;
  bf16* Hl = (bf16*)(ws + off); off += (size_t)64 * 1024 * 2;
  bf16* Nh = (bf16*)(ws + off); off += (size_t)64 * 1024 * 2;
  bf16* Nl = (bf16*)(ws + off); off += (size_t)64 * 1024 * 2;
  float* xM = (float*)(ws + off); off += (size_t)64 * 1024 * 4;   // 256 KB each
  float* hM = (float*)(ws + off); off += (size_t)64 * 1024 * 4;
  float* cM = (float*)(ws + off); off += (size_t)64 * 1024 * 4;
  float* zbuf = (float*)(ws + off); off += (size_t)64 * 4096 * 4; // 1 MB

  prep<<<512, 256, 0, stream>>>(Q, R, Qh, Ql, Rh, Rl, hM, cM, Nh, Nl);
  for (int t = 0; t < 512; ++t) {
    const float* xt = x + (size_t)t * 65536;
    // P1: x1 = 2*sig(h_new @ Q^T) * x_t
    mog_phase<<<256, 1024, 0, stream>>>(Nh, Nl, Qh, Ql, xt, xM, Xh, Xl);
    // P2: h2 = 2*sig(x1 @ R^T) * h_prev
    mog_phase<<<256, 1024, 0, stream>>>(Xh, Xl, Rh, Rl, hM, hM, Hh, Hl);
    // P3: x3 = 2*sig(h2 @ Q^T) * x1
    mog_phase<<<256, 1024, 0, stream>>>(Hh, Hl, Qh, Ql, xM, xM, Xh, Xl);
    // P4: h4 = 2*sig(x3 @ R^T) * h2
    mog_phase<<<256, 1024, 0, stream>>>(Xh, Xl, Rh, Rl, hM, hM, Hh, Hl);
    // node5: P5 (x5) || z_h = h4 @ W_h^T -> zbuf
    mog5_zh<<<512, 1024, 0, stream>>>(Hh, Hl, Qh, Ql, xM, xM, Xh, Xl,
                                      Wall, zbuf);
    // node6: z = x5 @ W_x^T + zbuf + b -> LSTM update
    gate_x<<<256, 1024, 0, stream>>>(Xh, Xl, Wall, zbuf, ball, cM, hM,
                                     Nh, Nl, out, t);
  }
}

// Round 13
// 27024.976 us; speedup vs baseline: 1.0513x; 1.0513x over previous
//
#include <hip/hip_runtime.h>
#include <hip/hip_bf16.h>
#include <math.h>

// MogLSTM S=512, B=64, E=H=1024. R13: r11's best 6-node graph, with ALL
// activation operands kept only as f32 masters; every GEMM splits A (and W)
// to bf16 hi/lo in-register (bit-identical to the stored-band arithmetic,
// same read bytes, half the epilogue stores, fewer streams/buffers).
// Buffers: Qh/Ql/Rh/Rl (prep-split, 8MB) + xM/hM/nM/cM f32 masters (1MB).
// Node chain per step: P1..P5 (mog) -> gate (GEMM K=2048 + LSTM update).

using bf16   = __bf16;
using bf16x8 = __attribute__((ext_vector_type(8))) __bf16;
using f32x4  = __attribute__((ext_vector_type(4))) float;

#define MFMA16(a,b,c) __builtin_amdgcn_mfma_f32_16x16x32_bf16((a),(b),(c),0,0,0)

__device__ __forceinline__ float fsig(float x) { return 1.f / (1.f + expf(-x)); }

// in-register hi/lo split of 8 consecutive f32 -> two bf16x8 fragments.
// Bit-identical to prep-split bands: hi = bf16(v), lo = bf16(v - hi).
__device__ __forceinline__ void split8(const float* __restrict__ p,
                                       bf16x8& ah, bf16x8& al) {
  f32x4 v0 = *(const f32x4*)p;
  f32x4 v1 = *(const f32x4*)(p + 4);
#pragma unroll
  for (int e = 0; e < 4; ++e) {
    bf16 h0 = (bf16)v0[e]; ah[e] = h0;     al[e] = (bf16)(v0[e] - (float)h0);
    bf16 h1 = (bf16)v1[e]; ah[4 + e] = h1; al[4 + e] = (bf16)(v1[e] - (float)h1);
  }
}

// ---------------- prologue: Q/R hi+lo split, zero state ----------------
__global__ void prep(const float* __restrict__ Q, const float* __restrict__ R,
                     bf16* __restrict__ Qh, bf16* __restrict__ Ql,
                     bf16* __restrict__ Rh, bf16* __restrict__ Rl,
                     float* __restrict__ nM, float* __restrict__ cM) {
  const long tid = (long)blockIdx.x * blockDim.x + threadIdx.x;
  const long nth = (long)gridDim.x * blockDim.x;
  for (long i = tid; i < 1024L * 1024 / 4; i += nth) {
    float4 v = ((const float4*)Q)[i];
    bf16 a0 = (bf16)v.x, a1 = (bf16)v.y, a2 = (bf16)v.z, a3 = (bf16)v.w;
    Qh[i*4+0] = a0; Qh[i*4+1] = a1; Qh[i*4+2] = a2; Qh[i*4+3] = a3;
    Ql[i*4+0] = (bf16)(v.x - (float)a0); Ql[i*4+1] = (bf16)(v.y - (float)a1);
    Ql[i*4+2] = (bf16)(v.z - (float)a2); Ql[i*4+3] = (bf16)(v.w - (float)a3);
    float4 u = ((const float4*)R)[i];
    bf16 b0 = (bf16)u.x, b1 = (bf16)u.y, b2 = (bf16)u.z, b3 = (bf16)u.w;
    Rh[i*4+0] = b0; Rh[i*4+1] = b1; Rh[i*4+2] = b2; Rh[i*4+3] = b3;
    Rl[i*4+0] = (bf16)(u.x - (float)b0); Rl[i*4+1] = (bf16)(u.y - (float)b1);
    Rl[i*4+2] = (bf16)(u.z - (float)b2); Rl[i*4+3] = (bf16)(u.w - (float)b3);
  }
  for (long i = tid; i < 64L * 1024; i += nth) {
    nM[i] = 0.f; cM[i] = 0.f;
  }
}

// ---------------- mogrifier phase ----------------
// dst = 2*sig(A @ B^T) * mult. Grid 256 WGs x 512 thr (r11 shape).
// mt = bid>>6 (16-row M tile), c = bid&63 (16-col N tile), wave w (0..7) =
// K-slice of 128 (4 ksteps). A read from f32 master, split in-register.
// C-frag mapping (verified r9-r12): col = 16c + (l&15), row = 16mt + (l>>4)*4 + q.
__global__ __launch_bounds__(512) void mog_phase(
    const float* __restrict__ Af, const bf16* __restrict__ Bh,
    const bf16* __restrict__ Bl, const float* __restrict__ mult,
    float* __restrict__ dstM) {
  __shared__ f32x4 red[7][64];
  const int mt = blockIdx.x >> 6, c = blockIdx.x & 63;
  const int tid = threadIdx.x, l = tid & 63, w = tid >> 6;
  const int r16 = l & 15, kg = l >> 4;
  const size_t kb = (size_t)w * 128 + kg * 8;
  const bf16*  bhp = Bh + (size_t)(16 * c + r16) * 1024 + kb;
  const bf16*  blp = Bl + (size_t)(16 * c + r16) * 1024 + kb;
  const float* afp = Af + (size_t)(16 * mt + r16) * 1024 + kb;
  f32x4 acc = {};
#pragma unroll
  for (int ks = 0; ks < 4; ++ks) {
    bf16x8 bh = *(const bf16x8*)(bhp + ks * 32);
    bf16x8 bl = *(const bf16x8*)(blp + ks * 32);
    bf16x8 ah, al;
    split8(afp + ks * 32, ah, al);
    acc = MFMA16(al, bl, acc);
    acc = MFMA16(al, bh, acc);
    acc = MFMA16(ah, bl, acc);
    acc = MFMA16(ah, bh, acc);
  }
  if (w) red[w - 1][l] = acc;
  __syncthreads();
  if (w == 0) {
#pragma unroll
    for (int kk = 0; kk < 7; ++kk) acc += red[kk][l];
    const int col = 16 * c + r16;
#pragma unroll
    for (int q = 0; q < 4; ++q) {
      const int row = 16 * mt + kg * 4 + q;
      const size_t idx = (size_t)row * 1024 + col;
      dstM[idx] = 2.f * fsig(acc[q]) * mult[idx];
    }
  }
}

// ---------------- fused gate GEMM + LSTM update (r11 structure) -----------
// Grid 256 WGs x 512 thr: WG g owns hcols 4g..4g+3 for all 4 gates.
// B-col r16 -> W row (r16>>2)*1024 + 4g + (r16&3); W read once per step.
// Wave w (0..7) = K-slice of 256: w<4 -> x half (xM), w>=4 -> h half (hM).
// A and W both f32, split in-register. Epilogue = r11 verbatim lane math.
__global__ __launch_bounds__(512) void gate4(
    const float* __restrict__ xMf, const float* __restrict__ hMf,
    const float* __restrict__ Wf, const float* __restrict__ ball,
    float* __restrict__ cM, float* __restrict__ nM,
    float* __restrict__ out, int t) {
  __shared__ f32x4 red[8][4][64];   // 32 KB
  const int g = blockIdx.x;
  const int tid = threadIdx.x, l = tid & 63, w = tid >> 6;
  const int r16 = l & 15, kg = l >> 4;
  const float* Abf = (w < 4) ? xMf : hMf;
  const size_t kb = (size_t)(w & 3) * 256 + kg * 8;
  const size_t wrow = (size_t)(r16 >> 2) * 1024 + 4 * g + (r16 & 3);
  const float* wp = Wf + wrow * 2048 + (size_t)w * 256 + kg * 8;
  f32x4 acc[4] = {};
#pragma unroll
  for (int ks = 0; ks < 8; ++ks) {
    bf16x8 bh, bl;
    split8(wp + ks * 32, bh, bl);
#pragma unroll
    for (int m = 0; m < 4; ++m) {
      bf16x8 ah, al;
      split8(Abf + (size_t)(16 * m + r16) * 1024 + kb + ks * 32, ah, al);
      acc[m] = MFMA16(al, bl, acc[m]);
      acc[m] = MFMA16(al, bh, acc[m]);
      acc[m] = MFMA16(ah, bl, acc[m]);
      acc[m] = MFMA16(ah, bh, acc[m]);
    }
  }
#pragma unroll
  for (int m = 0; m < 4; ++m) red[w][m][l] = acc[m];
  __syncthreads();
  if (tid < 256) {
    const int row = tid >> 2, hc = tid & 3;
    const int m = row >> 4, rem = row & 15;
    const int kgq = rem >> 2, q = rem & 3;
    const int hcg = 4 * g + hc;
    float z[4];
#pragma unroll
    for (int gg = 0; gg < 4; ++gg) {
      const int lane = kgq * 16 + gg * 4 + hc;
      float s = red[0][m][lane][q];
#pragma unroll
      for (int kk = 1; kk < 8; ++kk) s += red[kk][m][lane][q];
      z[gg] = s + ball[gg * 1024 + hcg];
    }
    const size_t idx = (size_t)row * 1024 + hcg;
    const float cc = fsig(z[1]) * cM[idx] + fsig(z[0]) * tanhf(z[2]);
    const float hh = fsig(z[3]) * tanhf(cc);
    cM[idx] = cc;
    nM[idx] = hh;
    out[(size_t)t * 65536 + idx] = hh;
    if (t == 511) {
      out[(size_t)512 * 65536 + idx] = hh;
      out[(size_t)512 * 65536 + 65536 + idx] = cc;
    }
  }
}

extern "C" void kernel_launch(void* const* d_in, const int* in_sizes, int n_in,
                              void* d_out, int out_size, void* d_ws, size_t ws_size,
                              hipStream_t stream) {
  (void)in_sizes; (void)n_in; (void)out_size; (void)ws_size;
  const float* x    = (const float*)d_in[0];
  const float* Wall = (const float*)d_in[1];
  const float* ball = (const float*)d_in[2];
  const float* Q    = (const float*)d_in[3];
  const float* R    = (const float*)d_in[4];
  float* out = (float*)d_out;

  char* ws = (char*)d_ws;
  size_t off = 0;
  bf16* Qh = (bf16*)(ws + off); off += (size_t)1024 * 1024 * 2;   // 2 MB
  bf16* Ql = (bf16*)(ws + off); off += (size_t)1024 * 1024 * 2;
  bf16* Rh = (bf16*)(ws + off); off += (size_t)1024 * 1024 * 2;
  bf16* Rl = (bf16*)(ws + off); off += (size_t)1024 * 1024 * 2;
  float* xM = (float*)(ws + off); off += (size_t)64 * 1024 * 4;   // 256 KB each
  float* hM = (float*)(ws + off); off += (size_t)64 * 1024 * 4;
  float* nM = (float*)(ws + off); off += (size_t)64 * 1024 * 4;
  float* cM = (float*)(ws + off); off += (size_t)64 * 1024 * 4;

  prep<<<512, 256, 0, stream>>>(Q, R, Qh, Ql, Rh, Rl, nM, cM);
  for (int t = 0; t < 512; ++t) {
    const float* xt = x + (size_t)t * 65536;
    // P1: x1 = 2*sig(h_new @ Q^T) * x_t     (A=nM, mult=x_t  -> xM)
    mog_phase<<<256, 512, 0, stream>>>(nM, Qh, Ql, xt, xM);
    // P2: h2 = 2*sig(x1 @ R^T) * h_new      (A=xM, mult=nM   -> hM)
    mog_phase<<<256, 512, 0, stream>>>(xM, Rh, Rl, nM, hM);
    // P3: x3 = 2*sig(h2 @ Q^T) * x1         (A=hM, mult=xM   -> xM)
    mog_phase<<<256, 512, 0, stream>>>(hM, Qh, Ql, xM, xM);
    // P4: h4 = 2*sig(x3 @ R^T) * h2         (A=xM, mult=hM   -> hM)
    mog_phase<<<256, 512, 0, stream>>>(xM, Rh, Rl, hM, hM);
    // P5: x5 = 2*sig(h4 @ Q^T) * x3         (A=hM, mult=xM   -> xM)
    mog_phase<<<256, 512, 0, stream>>>(hM, Qh, Ql, xM, xM);
    // gate: z = [x5,h4]@W^T + b -> LSTM     (A=xM,hM -> cM, nM, out)
    gate4<<<256, 512, 0, stream>>>(xM, hM, Wall, ball, cM, nM, out, t);
  }
}